// Round 1
// baseline (261.046 us; speedup 1.0000x reference)
//
#include <hip/hip_runtime.h>

// Problem constants (from reference setup_inputs)
#define Bn 16
#define Yn 32
#define Hn 256
#define Wn 256
#define HWn (Hn * Wn)          // 65536
#define NPIX (Bn * HWn)        // 1,048,576 pixels
#define DIST_IND_F 7.0f

// Per-pixel scale: loss/Y then mean over B*H*W -> 1/(Y*NPIX) = 2^-25 (exact)
#define OUT_SCALE (1.0f / ((float)Yn * (float)NPIX))

__device__ __forceinline__ void regress_f(float n, float sx, float sxx,
                                          float sy, float sxy,
                                          float& slope, float& inter, bool& valid) {
    valid = (n >= 3.0f);
    float n_safe = fmaxf(n, 1.0f);
    float cov = sxy - sx * sy / n_safe;
    float var = sxx - sx * sx / n_safe;
    float var_safe = (var > 0.0f) ? var : 1.0f;
    float s = cov / var_safe;
    s = fminf(fmaxf(s, 0.0f), 2.0f);   // clip [SLOPE_MIN, SLOPE_MAX]
    slope = s;
    inter = (sy - s * sx) / n_safe;
}

__global__ __launch_bounds__(256)
void DisturbanceRegressionLoss_kernel(const float* __restrict__ out,
                                      float* __restrict__ loss_out) {
    const int p = blockIdx.x * 256 + threadIdx.x;     // pixel id in [0, NPIX)
    const int b = p >> 16;                            // p / HWn
    const int hw = p & (HWn - 1);                     // p % HWn
    const float* base = out + (size_t)b * (Yn * HWn) + hw;

    // Load the Y-column into registers (coalesced across the wave at each y).
    float v[Yn];
#pragma unroll
    for (int y = 0; y < Yn; ++y) v[y] = base[(size_t)y * HWn];

    // diff: d[0] = -7, d[1] = 0, d[Y-1] = 0, else v[y]-v[y-1]; argmin (first occurrence)
    float dmin = -DIST_IND_F;
    int idx = 0;
#pragma unroll
    for (int y = 2; y < Yn - 1; ++y) {
        float d = v[y] - v[y - 1];
        if (d < dmin) { dmin = d; idx = y; }          // strict < keeps first min
    }

    // Data-dependent sums (predicated; matches reference's masked fp32 einsum
    // since masked terms contribute exact 0.0f)
    float sy_b = 0.0f, sxy_b = 0.0f, sy_a = 0.0f, sxy_a = 0.0f;
#pragma unroll
    for (int t = 0; t < Yn; ++t) {
        bool bef = (t < idx);
        float xb = (float)t;
        float xa = (float)(t - idx);
        if (bef) { sy_b += v[t]; sxy_b += xb * v[t]; }
        else     { sy_a += v[t]; sxy_a += xa * v[t]; }
    }

    // Closed-form n/sx/sxx (exact integers, identical to fp32 mask-sums)
    const int nb = idx;
    const int na = Yn - idx;
    const float fn_b = (float)nb;
    const float fn_a = (float)na;
    const float sx_b  = (float)((nb * (nb - 1)) / 2);
    const float sxx_b = (float)(((nb - 1) * nb * (2 * nb - 1)) / 6);
    const float sx_a  = (float)((na * (na - 1)) / 2);
    const float sxx_a = (float)(((na - 1) * na * (2 * na - 1)) / 6);

    float slope_b, int_b, slope_a, int_a;
    bool val_b, val_a;
    regress_f(fn_b, sx_b, sxx_b, sy_b, sxy_b, slope_b, int_b, val_b);
    regress_f(fn_a, sx_a, sxx_a, sy_a, sxy_a, slope_a, int_a, val_a);

    // Residual SSE per segment
    float res_b = 0.0f, res_a = 0.0f;
#pragma unroll
    for (int t = 0; t < Yn; ++t) {
        float pb = slope_b * (float)t + int_b;
        float pa = slope_a * (float)(t - idx) + int_a;
        float rb = v[t] - pb;
        float ra = v[t] - pa;
        if (t < idx) res_b += rb * rb;
        else         res_a += ra * ra;
    }

    float loss = (val_b ? res_b : 0.0f) + (val_a ? res_a : 0.0f);

    // Block reduction: wave shuffle (64 lanes) -> LDS (4 waves) -> 1 atomic/block
#pragma unroll
    for (int off = 32; off > 0; off >>= 1)
        loss += __shfl_down(loss, off, 64);

    __shared__ float smem[4];
    const int lane = threadIdx.x & 63;
    const int wid  = threadIdx.x >> 6;
    if (lane == 0) smem[wid] = loss;
    __syncthreads();
    if (threadIdx.x == 0) {
        float s = smem[0] + smem[1] + smem[2] + smem[3];
        atomicAdd(loss_out, s * OUT_SCALE);
    }
}

extern "C" void kernel_launch(void* const* d_in, const int* in_sizes, int n_in,
                              void* d_out, int out_size, void* d_ws, size_t ws_size,
                              hipStream_t stream) {
    const float* out_in = (const float*)d_in[0];   // 'out' input; 'target' (d_in[1]) is unused
    float* loss = (float*)d_out;

    // d_out is poisoned 0xAA before every launch -> zero it (stream memset is capturable)
    hipMemsetAsync(loss, 0, sizeof(float) * (size_t)out_size, stream);

    dim3 grid(NPIX / 256), block(256);
    DisturbanceRegressionLoss_kernel<<<grid, block, 0, stream>>>(out_in, loss);
}

// Round 2
// 247.076 us; speedup vs baseline: 1.0565x; 1.0565x over previous
//
#include <hip/hip_runtime.h>

// Problem constants (from reference setup_inputs)
#define Bn 16
#define Yn 32
#define Hn 256
#define Wn 256
#define HWn (Hn * Wn)          // 65536
#define NPIX (Bn * HWn)        // 1,048,576 pixels
#define DIST_IND_F 7.0f

// Per-pixel scale: loss/Y then mean over B*H*W -> 1/(Y*NPIX) = 2^-25 (exact)
#define OUT_SCALE (1.0f / ((float)Yn * (float)NPIX))

__device__ __forceinline__ void regress_f(float n, float sx, float sxx,
                                          float sy, float sxy,
                                          float& slope, float& inter, bool& valid) {
    valid = (n >= 3.0f);
    float n_safe = fmaxf(n, 1.0f);
    float cov = sxy - sx * sy / n_safe;
    float var = sxx - sx * sx / n_safe;
    float var_safe = (var > 0.0f) ? var : 1.0f;
    float s = cov / var_safe;
    s = fminf(fmaxf(s, 0.0f), 2.0f);   // clip [SLOPE_MIN, SLOPE_MAX]
    slope = s;
    inter = (sy - s * sx) / n_safe;
}

// Per-pixel loss given the Y-column in registers. Identical fp32 op sequence
// to the verified scalar kernel (absmax was 0.0).
__device__ __forceinline__ float pixel_loss(const float* v) {
    // diff: d[0] = -7, d[1] = 0, d[Y-1] = 0, else v[y]-v[y-1]; first argmin
    float dmin = -DIST_IND_F;
    int idx = 0;
#pragma unroll
    for (int y = 2; y < Yn - 1; ++y) {
        float d = v[y] - v[y - 1];
        if (d < dmin) { dmin = d; idx = y; }          // strict < keeps first min
    }

    float sy_b = 0.0f, sxy_b = 0.0f, sy_a = 0.0f, sxy_a = 0.0f;
#pragma unroll
    for (int t = 0; t < Yn; ++t) {
        bool bef = (t < idx);
        float xb = (float)t;
        float xa = (float)(t - idx);
        if (bef) { sy_b += v[t]; sxy_b += xb * v[t]; }
        else     { sy_a += v[t]; sxy_a += xa * v[t]; }
    }

    const int nb = idx;
    const int na = Yn - idx;
    const float sx_b  = (float)((nb * (nb - 1)) / 2);
    const float sxx_b = (float)(((nb - 1) * nb * (2 * nb - 1)) / 6);
    const float sx_a  = (float)((na * (na - 1)) / 2);
    const float sxx_a = (float)(((na - 1) * na * (2 * na - 1)) / 6);

    float slope_b, int_b, slope_a, int_a;
    bool val_b, val_a;
    regress_f((float)nb, sx_b, sxx_b, sy_b, sxy_b, slope_b, int_b, val_b);
    regress_f((float)na, sx_a, sxx_a, sy_a, sxy_a, slope_a, int_a, val_a);

    float res_b = 0.0f, res_a = 0.0f;
#pragma unroll
    for (int t = 0; t < Yn; ++t) {
        float pb = slope_b * (float)t + int_b;
        float pa = slope_a * (float)(t - idx) + int_a;
        float rb = v[t] - pb;
        float ra = v[t] - pa;
        if (t < idx) res_b += rb * rb;
        else         res_a += ra * ra;
    }

    return (val_b ? res_b : 0.0f) + (val_a ? res_a : 0.0f);
}

__global__ __launch_bounds__(256)
void DisturbanceRegressionLoss_kernel(const float* __restrict__ out,
                                      float* __restrict__ loss_out) {
    // Each thread handles 4 consecutive w-pixels: float4 loads, 1 KiB/wave/y.
    const int g = blockIdx.x * 256 + threadIdx.x;     // group id in [0, NPIX/4)
    const int b = g >> 14;                            // (g*4) / HWn
    const int hw4 = g & ((HWn / 4) - 1);              // float4 index within image
    const float4* base = (const float4*)(out + (size_t)b * (Yn * HWn)) + hw4;

    float4 v4[Yn];
#pragma unroll
    for (int y = 0; y < Yn; ++y) v4[y] = base[(size_t)y * (HWn / 4)];

    float loss = 0.0f;
#pragma unroll
    for (int c = 0; c < 4; ++c) {
        float v[Yn];
#pragma unroll
        for (int y = 0; y < Yn; ++y) {
            // c is compile-time constant after unroll -> pure register select
            v[y] = (c == 0) ? v4[y].x : (c == 1) ? v4[y].y : (c == 2) ? v4[y].z : v4[y].w;
        }
        loss += pixel_loss(v);
    }

    // Block reduction: wave shuffle (64 lanes) -> LDS (4 waves) -> 1 atomic/block
#pragma unroll
    for (int off = 32; off > 0; off >>= 1)
        loss += __shfl_down(loss, off, 64);

    __shared__ float smem[4];
    const int lane = threadIdx.x & 63;
    const int wid  = threadIdx.x >> 6;
    if (lane == 0) smem[wid] = loss;
    __syncthreads();
    if (threadIdx.x == 0) {
        float s = smem[0] + smem[1] + smem[2] + smem[3];
        atomicAdd(loss_out, s * OUT_SCALE);
    }
}

extern "C" void kernel_launch(void* const* d_in, const int* in_sizes, int n_in,
                              void* d_out, int out_size, void* d_ws, size_t ws_size,
                              hipStream_t stream) {
    const float* out_in = (const float*)d_in[0];   // 'out' input; 'target' (d_in[1]) is unused
    float* loss = (float*)d_out;

    // d_out is poisoned 0xAA before every launch -> zero it (stream memset is capturable)
    hipMemsetAsync(loss, 0, sizeof(float) * (size_t)out_size, stream);

    dim3 grid(NPIX / 4 / 256), block(256);
    DisturbanceRegressionLoss_kernel<<<grid, block, 0, stream>>>(out_in, loss);
}

// Round 3
// 244.476 us; speedup vs baseline: 1.0678x; 1.0106x over previous
//
#include <hip/hip_runtime.h>

// Problem constants (from reference setup_inputs)
#define Bn 16
#define Yn 32
#define Hn 256
#define Wn 256
#define HWn (Hn * Wn)          // 65536
#define NPIX (Bn * HWn)        // 1,048,576 pixels
#define DIST_IND_F 7.0f

// Per-pixel scale: loss/Y then mean over B*H*W -> 1/(Y*NPIX) = 2^-25 (exact)
#define OUT_SCALE (1.0f / ((float)Yn * (float)NPIX))

__device__ __forceinline__ void regress_f(float n, float sx, float sxx,
                                          float sy, float sxy,
                                          float& slope, float& inter, bool& valid) {
    valid = (n >= 3.0f);
    float n_safe = fmaxf(n, 1.0f);
    float cov = sxy - sx * sy / n_safe;
    float var = sxx - sx * sx / n_safe;
    float var_safe = (var > 0.0f) ? var : 1.0f;
    float s = cov / var_safe;
    s = fminf(fmaxf(s, 0.0f), 2.0f);   // clip [SLOPE_MIN, SLOPE_MAX]
    slope = s;
    inter = (sy - s * sx) / n_safe;
}

// Streaming formulation: one pass over y maintaining running sufficient
// statistics (Σv, Σt·v, Σv²) per pixel; on each new diff-minimum, snapshot
// the prefix sums (these ARE the "before"-segment sums since mb = t < idx).
// Residual SSE recovered in closed form:
//   res = Σv² - 2sΣxv - 2iΣv + s²Σx² + 2siΣx + i²n
// This avoids buffering the whole Y-column (VGPR 170 -> ~115), enabling
// 4 waves/SIMD (16 waves/CU) with the grid exactly fully resident.
__global__ __launch_bounds__(256, 4)
void DisturbanceRegressionLoss_kernel(const float* __restrict__ out,
                                      float* __restrict__ loss_out) {
    const int g = blockIdx.x * 256 + threadIdx.x;     // float4-group id
    const int b = g >> 14;                            // (g*4) / HWn
    const int hw4 = g & ((HWn / 4) - 1);              // float4 index within image
    const float4* base = (const float4*)(out + (size_t)b * (Yn * HWn)) + hw4;
    const size_t stride = HWn / 4;

    // Per-component (4 pixels/thread) streaming state
    float vprev[4], dmin[4], s1[4], sx1[4], svv[4], s1b[4], sxb[4], svvb[4];
    int idx[4];
#pragma unroll
    for (int c = 0; c < 4; ++c) {
        vprev[c] = 0.0f; dmin[c] = -DIST_IND_F;
        s1[c] = 0.0f; sx1[c] = 0.0f; svv[c] = 0.0f;
        s1b[c] = 0.0f; sxb[c] = 0.0f; svvb[c] = 0.0f;
        idx[c] = 0;
    }

    // Explicit 2-deep chunk pipeline: load chunk k+1 while processing chunk k.
    float4 buf[2][8];
#pragma unroll
    for (int j = 0; j < 8; ++j) buf[0][j] = base[(size_t)j * stride];

#pragma unroll
    for (int k = 0; k < 4; ++k) {
        if (k < 3) {
#pragma unroll
            for (int j = 0; j < 8; ++j)
                buf[(k + 1) & 1][j] = base[(size_t)((k + 1) * 8 + j) * stride];
        }
#pragma unroll
        for (int j = 0; j < 8; ++j) {
            const int t = k * 8 + j;                  // compile-time constant
            const float tf = (float)t;
            float4 vv = buf[k & 1][j];
            float vc[4] = {vv.x, vv.y, vv.z, vv.w};
#pragma unroll
            for (int c = 0; c < 4; ++c) {
                float v = vc[c];
                if (t >= 2 && t <= 30) {              // diff check window
                    float d = v - vprev[c];           // same fp32 diff as ref
                    if (d < dmin[c]) {                // strict < : first argmin
                        dmin[c] = d; idx[c] = t;
                        s1b[c] = s1[c];               // prefix sums over t' < t
                        sxb[c] = sx1[c];
                        svvb[c] = svv[c];
                    }
                }
                s1[c] += v;
                sx1[c] = fmaf(tf, v, sx1[c]);
                svv[c] = fmaf(v, v, svv[c]);
                vprev[c] = v;
            }
        }
    }

    // Epilogue: closed-form regressions + residuals per pixel
    float loss = 0.0f;
#pragma unroll
    for (int c = 0; c < 4; ++c) {
        const int nb = idx[c];
        const int na = Yn - nb;
        const float fnb = (float)nb, fna = (float)na;
        const float sx_b  = (float)((nb * (nb - 1)) / 2);
        const float sxx_b = (float)(((nb - 1) * nb * (2 * nb - 1)) / 6);
        const float sx_a  = (float)((na * (na - 1)) / 2);
        const float sxx_a = (float)(((na - 1) * na * (2 * na - 1)) / 6);

        const float sy_b  = s1b[c];
        const float sxy_b = sxb[c];
        const float svv_b = svvb[c];
        const float sy_a  = s1[c] - sy_b;
        const float sxy_a = (sx1[c] - sxb[c]) - fnb * sy_a;  // x = t - idx
        const float svv_a = svv[c] - svv_b;

        float slope_b, int_b, slope_a, int_a;
        bool val_b, val_a;
        regress_f(fnb, sx_b, sxx_b, sy_b, sxy_b, slope_b, int_b, val_b);
        regress_f(fna, sx_a, sxx_a, sy_a, sxy_a, slope_a, int_a, val_a);

        float res_b = svv_b - 2.0f * slope_b * sxy_b - 2.0f * int_b * sy_b
                    + slope_b * slope_b * sxx_b
                    + 2.0f * slope_b * int_b * sx_b
                    + int_b * int_b * fnb;
        float res_a = svv_a - 2.0f * slope_a * sxy_a - 2.0f * int_a * sy_a
                    + slope_a * slope_a * sxx_a
                    + 2.0f * slope_a * int_a * sx_a
                    + int_a * int_a * fna;

        loss += (val_b ? res_b : 0.0f) + (val_a ? res_a : 0.0f);
    }

    // Block reduction: wave shuffle (64 lanes) -> LDS (4 waves) -> 1 atomic/block
#pragma unroll
    for (int off = 32; off > 0; off >>= 1)
        loss += __shfl_down(loss, off, 64);

    __shared__ float smem[4];
    const int lane = threadIdx.x & 63;
    const int wid  = threadIdx.x >> 6;
    if (lane == 0) smem[wid] = loss;
    __syncthreads();
    if (threadIdx.x == 0) {
        float s = smem[0] + smem[1] + smem[2] + smem[3];
        atomicAdd(loss_out, s * OUT_SCALE);
    }
}

extern "C" void kernel_launch(void* const* d_in, const int* in_sizes, int n_in,
                              void* d_out, int out_size, void* d_ws, size_t ws_size,
                              hipStream_t stream) {
    const float* out_in = (const float*)d_in[0];   // 'out'; 'target' (d_in[1]) unused
    float* loss = (float*)d_out;

    // d_out is poisoned 0xAA before every launch -> zero it (stream memset is capturable)
    hipMemsetAsync(loss, 0, sizeof(float) * (size_t)out_size, stream);

    dim3 grid(NPIX / 4 / 256), block(256);   // 1024 blocks = exactly resident at 4 blocks/CU
    DisturbanceRegressionLoss_kernel<<<grid, block, 0, stream>>>(out_in, loss);
}